// Round 9
// baseline (114.055 us; speedup 1.0000x reference)
//
#include <hip/hip_runtime.h>

// Mutual information, N=8 images 384x384, 50 soft bins.
// K1 hgram: 28 even sigmoid edges per element (t_j = sigmoid(10v-0.2j), x256),
//   G = te_x . te_y^T via 16x16x32 MFMA (32x32-padded); each block plain-stores
//   its 28x28 partial G tile (no atomics, no ws zeroing needed).
// K2 finalize (1 block): sum 96 partials/image; hgram = W G W^T, W = D*M
//   (cubic-interp odd edges, 4-banded {1,7,-9,1}/16 even, {-1,9,-7,-1}/16 odd);
//   marginals telescope (sum_b W[b] = e_1 - e_26); MI log-sum.
//
// R9 vs R8: dropped the hipMemsetAsync dispatch and the 768x784 device-scope
// atomic epilogue — blocks store partials to ws (768x784 f32 = 2.4 MB, each
// element written exactly once so 0xAA poison is harmless), finalize reduces
// them (coalesced, ~1.5us). Budget: harness fill+overhead ~68us fixed floor;
// controllable was ~18.5us (hgram 13 + memset 3 + finalize 3).

#define D_TOTAL   147456
#define NBATCH    8
#define BINS      50
#define NEDGE     28                       // even edges j=-2..52
#define KSLICES   96                       // slices per image -> 768 blocks = 3/CU
#define KC        256                      // d-columns per block iteration
#define SLICE_LEN (D_TOTAL / KSLICES)      // 1536
#define ITERS     (SLICE_LEN / KC)         // 6
#define LDS_STR   280                      // 140 dwords = 12 mod 32: conflict-free b128 frags
#define PSZ       (NEDGE * NEDGE)          // 784 floats per partial tile

typedef _Float16 half8 __attribute__((ext_vector_type(8)));
typedef float    f32x4 __attribute__((ext_vector_type(4)));

struct Tab { float c[NEDGE]; };
constexpr Tab make_tab() {
    Tab t{};
    double c = 0.6703200460356393;          // e^{-0.4} (edge j=-2)
    const double lam = 1.4918246976412703;  // e^{0.4} between even edges
    for (int i = 0; i < NEDGE; ++i) { t.c[i] = (float)c; c *= lam; }
    return t;
}
constexpr Tab TAB = make_tab();

__global__ __launch_bounds__(256, 3) void hgram_kernel(const float* __restrict__ im1,
                                                       const float* __restrict__ im2,
                                                       float* __restrict__ partial) {
    __shared__ __align__(16) _Float16 Xs[32][LDS_STR];
    __shared__ __align__(16) _Float16 Ys[32][LDS_STR];

    const int tid   = threadIdx.x;
    const int slice = blockIdx.x;
    const int n     = blockIdx.y;
    const int base  = n * D_TOTAL + slice * SLICE_LEN;

    {   // zero pad rows 28..31 once (staging only rewrites rows 0..27)
        unsigned* px = (unsigned*)&Xs[28][0];
        unsigned* py = (unsigned*)&Ys[28][0];
        for (int i = tid; i < 4 * LDS_STR / 2; i += 256) { px[i] = 0u; py[i] = 0u; }
    }

    const int col  = tid;                     // 256 cols/iter; each thread stages X and Y
    const int lane = tid & 63;
    const int w    = tid >> 6;
    const int r0   = (w & 1) << 4;            // G row strip (X edge)
    const int c0   = (w >> 1) << 4;           // G col strip (Y edge)
    const int frow = lane & 15;
    const int kg   = (lane >> 4) << 3;

    f32x4 acc = {0.f, 0.f, 0.f, 0.f};

    float vx = im1[base + col];
    float vy = im2[base + col];
    for (int it = 0; it < ITERS; ++it) {
        float nvx = 0.f, nvy = 0.f;
        if (it + 1 < ITERS) {                          // prefetch: in flight during stage
            nvx = im1[base + (it + 1) * KC + col];
            nvy = im2[base + (it + 1) * KC + col];
        }
        // ---- stage both elements: 28 even-edge sigmoids each (x256, f16) ----
        {
            const float Ex = __builtin_amdgcn_exp2f(vx * -14.426950408889634f); // e^{-10vx}
            const float Ey = __builtin_amdgcn_exp2f(vy * -14.426950408889634f); // e^{-10vy}
            _Float16* dx = &Xs[0][col];
            _Float16* dy = &Ys[0][col];
            #pragma unroll
            for (int i = 0; i < NEDGE; i += 4) {
                #pragma unroll
                for (int q = 0; q < 4; ++q) {
                    const float c = TAB.c[i + q];      // compile-time literal
                    float ux = c * Ex;                 // independent off Ex/Ey only
                    float uy = c * Ey;
                    float tx = __builtin_amdgcn_rcpf(__builtin_fmaf(ux, 0.00390625f, 0.00390625f));
                    float ty = __builtin_amdgcn_rcpf(__builtin_fmaf(uy, 0.00390625f, 0.00390625f));
                    dx[(i + q) * LDS_STR] = (_Float16)tx;   // 256/(1+u)
                    dy[(i + q) * LDS_STR] = (_Float16)ty;
                }
            }
        }
        __syncthreads();
        #pragma unroll
        for (int ks = 0; ks < 8; ++ks) {
            const int k0 = ks * 32 + kg;
            half8 a = *(const half8*)&Xs[r0 + frow][k0];
            half8 b = *(const half8*)&Ys[c0 + frow][k0];
            acc = __builtin_amdgcn_mfma_f32_16x16x32_f16(a, b, acc, 0, 0, 0);
        }
        __syncthreads();
        vx = nvx; vy = nvy;
    }

    // epilogue: plain-store this block's 28x28 partial tile (each element once)
    float* p = partial + (n * KSLICES + slice) * PSZ;
    const int gj = c0 + (lane & 15);
    const int ri = r0 + ((lane >> 4) << 2);
    if (gj < NEDGE) {
        #pragma unroll
        for (int r = 0; r < 4; ++r) {
            const int gi = ri + r;
            if (gi < NEDGE) p[gi * NEDGE + gj] = acc[r];
        }
    }
}

__global__ __launch_bounds__(1024) void finalize_kernel(const float* __restrict__ partial,
                                                        float* __restrict__ out) {
    __shared__ float Gs[NBATCH][NEDGE][29];   // stride 29 vs bank conflicts
    __shared__ float mx[NBATCH][BINS], my[NBATCH][BINS];
    __shared__ float red[16];
    __shared__ float sT;
    const int tid = threadIdx.x;

    // reduce 96 partial tiles per image (coalesced: consecutive tid = consecutive rc)
    for (int idx = tid; idx < NBATCH * PSZ; idx += 1024) {
        const int n = idx / PSZ;
        const int rc = idx - n * PSZ;
        const float* p = partial + (size_t)n * KSLICES * PSZ + rc;
        float s = 0.f;
        #pragma unroll 8
        for (int sl = 0; sl < KSLICES; ++sl) s += p[sl * PSZ];
        const int r = rc / NEDGE, c = rc - r * NEDGE;
        Gs[n][r][c] = s;
    }
    __syncthreads();

    // marginals: 800 tasks, 4-MAC band-dot (W row applied to G*(e1-e26))
    if (tid < 2 * NBATCH * BINS) {
        const int which = (tid >= NBATCH * BINS) ? 1 : 0;
        const int t2 = which ? tid - NBATCH * BINS : tid;
        const int n = t2 / BINS, b = t2 - n * BINS;
        const int q = b >> 1;
        float w0, w1, w2, w3;
        if (b & 1) { w0 = -1.f; w1 = 9.f; w2 = -7.f; w3 = -1.f; }
        else       { w0 =  1.f; w1 = 7.f; w2 = -9.f; w3 =  1.f; }
        float m;
        if (which == 0) {
            m = w0 * (Gs[n][q][1]   - Gs[n][q][26])
              + w1 * (Gs[n][q+1][1] - Gs[n][q+1][26])
              + w2 * (Gs[n][q+2][1] - Gs[n][q+2][26])
              + w3 * (Gs[n][q+3][1] - Gs[n][q+3][26]);
            mx[n][b] = m * 0.0625f;
        } else {
            m = w0 * (Gs[n][1][q]   - Gs[n][26][q])
              + w1 * (Gs[n][1][q+1] - Gs[n][26][q+1])
              + w2 * (Gs[n][1][q+2] - Gs[n][26][q+2])
              + w3 * (Gs[n][1][q+3] - Gs[n][26][q+3]);
            my[n][b] = m * 0.0625f;
        }
    }
    if (tid == 0) {
        float t = 0.f;
        for (int n = 0; n < NBATCH; ++n)
            t += Gs[n][1][1] - Gs[n][1][26] - Gs[n][26][1] + Gs[n][26][26];
        sT = t;
    }
    __syncthreads();

    // MI pass: 2x2 entry blocks share one 4x4 G block (task = n, b-pair, c-pair)
    const float invT = 1.0f / sT;
    const float invT2 = invT * invT;
    float mi = 0.f;
    for (int task = tid; task < NBATCH * 25 * 25; task += 1024) {
        const int n = task / 625;
        const int rem = task - n * 625;
        const int bp = rem / 25, cp = rem - bp * 25;
        float g[4][4];
        #pragma unroll
        for (int r = 0; r < 4; ++r)
            #pragma unroll
            for (int s = 0; s < 4; ++s) g[r][s] = Gs[n][bp + r][cp + s];
        float rde[4], rdo[4];
        #pragma unroll
        for (int r = 0; r < 4; ++r) {
            rde[r] =  g[r][0] + 7.f * g[r][1] - 9.f * g[r][2] + g[r][3];
            rdo[r] = -g[r][0] + 9.f * g[r][1] - 7.f * g[r][2] - g[r][3];
        }
        const float hee = ( rde[0] + 7.f*rde[1] - 9.f*rde[2] + rde[3]) * (1.f/256.f);
        const float heo = ( rdo[0] + 7.f*rdo[1] - 9.f*rdo[2] + rdo[3]) * (1.f/256.f);
        const float hoe = (-rde[0] + 9.f*rde[1] - 7.f*rde[2] - rde[3]) * (1.f/256.f);
        const float hoo = (-rdo[0] + 9.f*rdo[1] - 7.f*rdo[2] - rdo[3]) * (1.f/256.f);
        const int b0 = 2 * bp, c0 = 2 * cp;
        {
            float p = hee * invT, jo = mx[n][b0] * my[n][c0] * invT2;
            mi += p * (__logf(p + 1e-8f) - __logf(jo + 1e-8f));
        }
        {
            float p = heo * invT, jo = mx[n][b0] * my[n][c0 + 1] * invT2;
            mi += p * (__logf(p + 1e-8f) - __logf(jo + 1e-8f));
        }
        {
            float p = hoe * invT, jo = mx[n][b0 + 1] * my[n][c0] * invT2;
            mi += p * (__logf(p + 1e-8f) - __logf(jo + 1e-8f));
        }
        {
            float p = hoo * invT, jo = mx[n][b0 + 1] * my[n][c0 + 1] * invT2;
            mi += p * (__logf(p + 1e-8f) - __logf(jo + 1e-8f));
        }
    }
    #pragma unroll
    for (int o = 32; o > 0; o >>= 1) mi += __shfl_down(mi, o, 64);
    if ((tid & 63) == 0) red[tid >> 6] = mi;
    __syncthreads();
    if (tid == 0) {
        float t = 0.f;
        for (int i = 0; i < 16; ++i) t += red[i];
        out[0] = t;
    }
}

extern "C" void kernel_launch(void* const* d_in, const int* in_sizes, int n_in,
                              void* d_out, int out_size, void* d_ws, size_t ws_size,
                              hipStream_t stream) {
    const float* im1 = (const float*)d_in[0];
    const float* im2 = (const float*)d_in[1];
    float* out = (float*)d_out;
    float* partial = (float*)d_ws;   // [8][96][784] f32 = 2.4 MB

    hgram_kernel<<<dim3(KSLICES, NBATCH), dim3(256), 0, stream>>>(im1, im2, partial);
    finalize_kernel<<<dim3(1), dim3(1024), 0, stream>>>(partial, out);
}

// Round 11
// 82.750 us; speedup vs baseline: 1.3783x; 1.3783x over previous
//
#include <hip/hip_runtime.h>

// Mutual information, N=8 images 384x384, 50 soft bins.
// K1 hgram: 28 even sigmoid edges per element (t_j = sigmoid(10v-0.2j), x256),
//   G = te_x . te_y^T via 16x16x32 MFMA (32x32-padded), atomic 28x28 epilogue
//   into hg[8][32][32] (zeroed by a 32KB memset dispatch).
// K2 finalize (1 block): hgram = W G W^T, W = D*M (cubic-interp odd edges,
//   4-banded {1,7,-9,1}/16 even, {-1,9,-7,-1}/16 odd); marginals telescope
//   (sum_b W[b] = e_1 - e_26); MI log-sum.
//
// R11 = R10 with the compile fix: cvt_pkrtz returns __fp16x2 (not _Float16x2);
// typedef matches the builtin now. Pair-packed staging: each thread stages TWO
// adjacent elements, v_cvt_pkrtz packs each edge pair, one ds_write_b32 instead
// of 2x ds_write_b16 (hgram is LDS-inst-bound: 288 -> 176 ds insts/block-iter).

#define D_TOTAL   147456
#define NBATCH    8
#define BINS      50
#define NEDGE     28                       // even edges j=-2..52
#define KSLICES   96                       // 768 blocks = 3/CU, single generation
#define KC        256                      // d-columns per block iteration
#define SLICE_LEN (D_TOTAL / KSLICES)      // 1536
#define ITERS     (SLICE_LEN / KC)         // 6
#define LDS_STR   280                      // 140 dwords = 12 mod 32: conflict-free b128 frags

typedef _Float16 half8  __attribute__((ext_vector_type(8)));
typedef __fp16   fp16x2 __attribute__((ext_vector_type(2)));   // cvt_pkrtz return type
typedef float    f32x4  __attribute__((ext_vector_type(4)));

struct Tab { float c[NEDGE]; };
constexpr Tab make_tab() {
    Tab t{};
    double c = 0.6703200460356393;          // e^{-0.4} (edge j=-2)
    const double lam = 1.4918246976412703;  // e^{0.4} between even edges
    for (int i = 0; i < NEDGE; ++i) { t.c[i] = (float)c; c *= lam; }
    return t;
}
constexpr Tab TAB = make_tab();

__global__ __launch_bounds__(256, 3) void hgram_kernel(const float* __restrict__ im1,
                                                       const float* __restrict__ im2,
                                                       float* __restrict__ hg) {
    __shared__ __align__(16) _Float16 Xs[32][LDS_STR];
    __shared__ __align__(16) _Float16 Ys[32][LDS_STR];

    const int tid   = threadIdx.x;
    const int slice = blockIdx.x;
    const int n     = blockIdx.y;
    const int base  = n * D_TOTAL + slice * SLICE_LEN;

    {   // zero pad rows 28..31 once (staging only rewrites rows 0..27)
        unsigned* px = (unsigned*)&Xs[28][0];
        unsigned* py = (unsigned*)&Ys[28][0];
        for (int i = tid; i < 4 * LDS_STR / 2; i += 256) { px[i] = 0u; py[i] = 0u; }
    }

    // staging: threads 0..127 stage X element-pair (2h, 2h+1); 128..255 stage Y
    const int h    = tid & 127;
    const int isY  = tid >> 7;
    const float2* src2 = (const float2*)((isY ? im2 : im1) + base);
    _Float16* plane = isY ? &Ys[0][0] : &Xs[0][0];
    _Float16* dst   = plane + 2 * h;            // pair base within row

    const int lane = tid & 63;
    const int w    = tid >> 6;
    const int r0   = (w & 1) << 4;              // G row strip (X edge)
    const int c0   = (w >> 1) << 4;             // G col strip (Y edge)
    const int frow = lane & 15;
    const int kg   = (lane >> 4) << 3;

    f32x4 acc = {0.f, 0.f, 0.f, 0.f};

    float2 v = src2[h];
    for (int it = 0; it < ITERS; ++it) {
        float2 nv = {0.f, 0.f};
        if (it + 1 < ITERS) nv = src2[(it + 1) * (KC / 2) + h];   // prefetch
        // ---- stage 2 elements: 28 even-edge sigmoids each (x256, f16, packed) ----
        {
            const float Ea = __builtin_amdgcn_exp2f(v.x * -14.426950408889634f); // e^{-10va}
            const float Eb = __builtin_amdgcn_exp2f(v.y * -14.426950408889634f); // e^{-10vb}
            #pragma unroll
            for (int i = 0; i < NEDGE; ++i) {
                const float c = TAB.c[i];       // compile-time literal
                float ta = __builtin_amdgcn_rcpf(__builtin_fmaf(c * Ea, 0.00390625f, 0.00390625f));
                float tb = __builtin_amdgcn_rcpf(__builtin_fmaf(c * Eb, 0.00390625f, 0.00390625f));
                fp16x2 p = __builtin_amdgcn_cvt_pkrtz(ta, tb);    // 256/(1+u) pair
                *(fp16x2*)(dst + i * LDS_STR) = p;                // one ds_write_b32
            }
        }
        __syncthreads();
        #pragma unroll
        for (int ks = 0; ks < 8; ++ks) {
            const int k0 = ks * 32 + kg;
            half8 a = *(const half8*)&Xs[r0 + frow][k0];
            half8 b = *(const half8*)&Ys[c0 + frow][k0];
            acc = __builtin_amdgcn_mfma_f32_16x16x32_f16(a, b, acc, 0, 0, 0);
        }
        __syncthreads();
        v = nv;
    }

    // epilogue: atomic-add the 28x28 region of G
    float* hgn = hg + n * 1024;
    const int gj = c0 + (lane & 15);
    const int ri = r0 + ((lane >> 4) << 2);
    if (gj < NEDGE) {
        #pragma unroll
        for (int r = 0; r < 4; ++r) {
            const int gi = ri + r;
            if (gi < NEDGE) atomicAdd(&hgn[gi * 32 + gj], acc[r]);
        }
    }
}

__global__ __launch_bounds__(1024) void finalize_kernel(const float* __restrict__ hg,
                                                        float* __restrict__ out) {
    __shared__ float Gs[NBATCH][NEDGE][29];   // stride 29 vs bank conflicts
    __shared__ float mx[NBATCH][BINS], my[NBATCH][BINS];
    __shared__ float red[16];
    __shared__ float sT;
    const int tid = threadIdx.x;

    for (int idx = tid; idx < NBATCH * NEDGE * NEDGE; idx += 1024) {
        int n = idx / (NEDGE * NEDGE);
        int rem = idx - n * (NEDGE * NEDGE);
        int r = rem / NEDGE, c = rem - r * NEDGE;
        Gs[n][r][c] = hg[n * 1024 + r * 32 + c];
    }
    __syncthreads();

    // marginals: 800 tasks, 4-MAC band-dot (W row applied to G*(e1-e26))
    if (tid < 2 * NBATCH * BINS) {
        const int which = (tid >= NBATCH * BINS) ? 1 : 0;
        const int t2 = which ? tid - NBATCH * BINS : tid;
        const int n = t2 / BINS, b = t2 - n * BINS;
        const int q = b >> 1;
        float w0, w1, w2, w3;
        if (b & 1) { w0 = -1.f; w1 = 9.f; w2 = -7.f; w3 = -1.f; }
        else       { w0 =  1.f; w1 = 7.f; w2 = -9.f; w3 =  1.f; }
        float m;
        if (which == 0) {
            m = w0 * (Gs[n][q][1]   - Gs[n][q][26])
              + w1 * (Gs[n][q+1][1] - Gs[n][q+1][26])
              + w2 * (Gs[n][q+2][1] - Gs[n][q+2][26])
              + w3 * (Gs[n][q+3][1] - Gs[n][q+3][26]);
            mx[n][b] = m * 0.0625f;
        } else {
            m = w0 * (Gs[n][1][q]   - Gs[n][26][q])
              + w1 * (Gs[n][1][q+1] - Gs[n][26][q+1])
              + w2 * (Gs[n][1][q+2] - Gs[n][26][q+2])
              + w3 * (Gs[n][1][q+3] - Gs[n][26][q+3]);
            my[n][b] = m * 0.0625f;
        }
    }
    if (tid == 0) {
        float t = 0.f;
        for (int n = 0; n < NBATCH; ++n)
            t += Gs[n][1][1] - Gs[n][1][26] - Gs[n][26][1] + Gs[n][26][26];
        sT = t;
    }
    __syncthreads();

    // MI pass: 2x2 entry blocks share one 4x4 G block (task = n, b-pair, c-pair)
    const float invT = 1.0f / sT;
    const float invT2 = invT * invT;
    float mi = 0.f;
    for (int task = tid; task < NBATCH * 25 * 25; task += 1024) {
        const int n = task / 625;
        const int rem = task - n * 625;
        const int bp = rem / 25, cp = rem - bp * 25;
        float g[4][4];
        #pragma unroll
        for (int r = 0; r < 4; ++r)
            #pragma unroll
            for (int s = 0; s < 4; ++s) g[r][s] = Gs[n][bp + r][cp + s];
        float rde[4], rdo[4];
        #pragma unroll
        for (int r = 0; r < 4; ++r) {
            rde[r] =  g[r][0] + 7.f * g[r][1] - 9.f * g[r][2] + g[r][3];
            rdo[r] = -g[r][0] + 9.f * g[r][1] - 7.f * g[r][2] - g[r][3];
        }
        const float hee = ( rde[0] + 7.f*rde[1] - 9.f*rde[2] + rde[3]) * (1.f/256.f);
        const float heo = ( rdo[0] + 7.f*rdo[1] - 9.f*rdo[2] + rdo[3]) * (1.f/256.f);
        const float hoe = (-rde[0] + 9.f*rde[1] - 7.f*rde[2] - rde[3]) * (1.f/256.f);
        const float hoo = (-rdo[0] + 9.f*rdo[1] - 7.f*rdo[2] - rdo[3]) * (1.f/256.f);
        const int b0 = 2 * bp, c0 = 2 * cp;
        {
            float p = hee * invT, jo = mx[n][b0] * my[n][c0] * invT2;
            mi += p * (__logf(p + 1e-8f) - __logf(jo + 1e-8f));
        }
        {
            float p = heo * invT, jo = mx[n][b0] * my[n][c0 + 1] * invT2;
            mi += p * (__logf(p + 1e-8f) - __logf(jo + 1e-8f));
        }
        {
            float p = hoe * invT, jo = mx[n][b0 + 1] * my[n][c0] * invT2;
            mi += p * (__logf(p + 1e-8f) - __logf(jo + 1e-8f));
        }
        {
            float p = hoo * invT, jo = mx[n][b0 + 1] * my[n][c0 + 1] * invT2;
            mi += p * (__logf(p + 1e-8f) - __logf(jo + 1e-8f));
        }
    }
    #pragma unroll
    for (int o = 32; o > 0; o >>= 1) mi += __shfl_down(mi, o, 64);
    if ((tid & 63) == 0) red[tid >> 6] = mi;
    __syncthreads();
    if (tid == 0) {
        float t = 0.f;
        for (int i = 0; i < 16; ++i) t += red[i];
        out[0] = t;
    }
}

extern "C" void kernel_launch(void* const* d_in, const int* in_sizes, int n_in,
                              void* d_out, int out_size, void* d_ws, size_t ws_size,
                              hipStream_t stream) {
    const float* im1 = (const float*)d_in[0];
    const float* im2 = (const float*)d_in[1];
    float* out = (float*)d_out;
    float* hg  = (float*)d_ws;   // [8][32][32] f32 = 32 KB

    (void)hipMemsetAsync(d_ws, 0, NBATCH * 1024 * sizeof(float), stream);
    hgram_kernel<<<dim3(KSLICES, NBATCH), dim3(256), 0, stream>>>(im1, im2, hg);
    finalize_kernel<<<dim3(1), dim3(1024), 0, stream>>>(hg, out);
}